// Round 1
// baseline (570.131 us; speedup 1.0000x reference)
//
#include <hip/hip_runtime.h>

typedef unsigned short u16;
typedef __attribute__((ext_vector_type(8))) short bf16x8;
typedef __attribute__((ext_vector_type(4))) short bf16x4;
typedef __attribute__((ext_vector_type(4))) float f32x4;
typedef __attribute__((ext_vector_type(4))) unsigned short u16x4;

// Problem constants (fixed by the reference)
#define SEQ 1024
#define BSZ 8
#define NHD 16
#define DHD 64
#define DMODEL 1024

__device__ __forceinline__ u16 f2bf(float x) {
  unsigned u = __float_as_uint(x);
  return (u16)((u + 0x7fffu + ((u >> 16) & 1u)) >> 16);  // RNE
}
__device__ __forceinline__ float bf2f(u16 h) {
  return __uint_as_float(((unsigned)h) << 16);
}

typedef const __attribute__((address_space(1))) unsigned int gu32_t;
typedef __attribute__((address_space(3))) unsigned int lu32_t;
__device__ __forceinline__ void gload16(const void* g, void* l) {
  __builtin_amdgcn_global_load_lds((gu32_t*)g, (lu32_t*)l, 16, 0, 0);
}

// ---------------- cast / transpose kernels ----------------
__global__ void cast_w_k(const float* __restrict__ in, u16* __restrict__ out) {
  size_t i = ((size_t)blockIdx.x * 256 + threadIdx.x) * 4;
  float4 v = *(const float4*)(in + i);
  u16x4 o;
  o[0] = f2bf(v.x); o[1] = f2bf(v.y); o[2] = f2bf(v.z); o[3] = f2bf(v.w);
  *(u16x4*)(out + i) = o;
}

// in [R][C] f32 -> out [C][R] bf16
__global__ void transpose_cast_k(const float* __restrict__ in, u16* __restrict__ out,
                                 int R, int C) {
  __shared__ float tile[32][33];
  int tx = threadIdx.x & 31, ty = threadIdx.x >> 5;
  int bx = blockIdx.x * 32, by = blockIdx.y * 32;
#pragma unroll
  for (int rr = ty; rr < 32; rr += 8)
    tile[rr][tx] = in[(size_t)(by + rr) * C + bx + tx];
  __syncthreads();
#pragma unroll
  for (int rr = ty; rr < 32; rr += 8)
    out[(size_t)(bx + rr) * R + by + tx] = f2bf(tile[tx][rr]);
}

// r_emb [j][n][d] f32 -> [n][j][d] bf16
__global__ void cast_remb_k(const float* __restrict__ in, u16* __restrict__ out) {
  int t = blockIdx.x * 256 + threadIdx.x;  // (j*16+n)*8 + db
  int jn = t >> 3, db = t & 7;
  int j = jn >> 4, n = jn & 15;
  const float* src = in + (size_t)jn * 64 + db * 8;
  u16* dst = out + ((size_t)(n * 1024 + j)) * 64 + db * 8;
#pragma unroll
  for (int e = 0; e < 8; ++e) dst[e] = f2bf(src[e]);
}

// ---------------- GEMM: C[M,N] = A[M,K] @ Bt[N,K]^T  (bf16, 128x128 tile) ----------------
// EPI 0: scatter into q/k/v [b][h][seq][d] bf16.  EPI 1: yout = resid + C (f32).
template <int EPI>
__global__ __launch_bounds__(256) void gemm_bt(
    const u16* __restrict__ A, const u16* __restrict__ Bt, int K,
    u16* __restrict__ q_o, u16* __restrict__ k_o, u16* __restrict__ v_o,
    const float* __restrict__ resid, float* __restrict__ yout) {
  __shared__ __attribute__((aligned(16))) u16 ldsA[2][4096];  // [128 rows][32 k]
  __shared__ __attribute__((aligned(16))) u16 ldsB[2][4096];
  const int tid = threadIdx.x;
  const int wid = tid >> 6, l = tid & 63;
  const int l15 = l & 15, lg = l >> 4;
  const int bm = blockIdx.y, bn = blockIdx.x;
  const int wm = wid & 1, wn = wid >> 1;
  const size_t ldb = (size_t)K * 2;  // row bytes

  const char* aA = (const char*)A + (size_t)(bm * 128 + wid * 32 + (l >> 2)) * ldb + (l & 3) * 16;
  const char* aB = (const char*)Bt + (size_t)(bn * 128 + wid * 32 + (l >> 2)) * ldb + (l & 3) * 16;

  auto stage = [&](int buf, int kt) {
    const char* sa = aA + (size_t)kt * 64;
    const char* sb = aB + (size_t)kt * 64;
    char* la = (char*)&ldsA[buf][wid * 1024];
    char* lb = (char*)&ldsB[buf][wid * 1024];
    gload16(sa, la);
    gload16(sa + 16 * ldb, la + 1024);
    gload16(sb, lb);
    gload16(sb + 16 * ldb, lb + 1024);
  };

  f32x4 acc[4][4] = {};
  stage(0, 0);
  __syncthreads();
  const int NT = K >> 5;
  for (int t = 0; t < NT; ++t) {
    int cur = t & 1;
    if (t + 1 < NT) stage(cur ^ 1, t + 1);
    bf16x8 af[4], bfr[4];
#pragma unroll
    for (int mi = 0; mi < 4; ++mi)
      af[mi] = *(const bf16x8*)&ldsA[cur][(wm * 64 + mi * 16 + l15) * 32 + lg * 8];
#pragma unroll
    for (int ni = 0; ni < 4; ++ni)
      bfr[ni] = *(const bf16x8*)&ldsB[cur][(wn * 64 + ni * 16 + l15) * 32 + lg * 8];
#pragma unroll
    for (int mi = 0; mi < 4; ++mi)
#pragma unroll
      for (int ni = 0; ni < 4; ++ni)
        acc[mi][ni] = __builtin_amdgcn_mfma_f32_16x16x32_bf16(af[mi], bfr[ni], acc[mi][ni], 0, 0, 0);
    __syncthreads();
  }

  if (EPI == 0) {
#pragma unroll
    for (int mi = 0; mi < 4; ++mi)
#pragma unroll
      for (int ni = 0; ni < 4; ++ni) {
        int c = bn * 128 + wn * 64 + ni * 16 + l15;
        int which = c >> 10, rem = c & 1023, h = rem >> 6, d = rem & 63;
        u16* dst = which == 0 ? q_o : (which == 1 ? k_o : v_o);
#pragma unroll
        for (int r = 0; r < 4; ++r) {
          int rg = bm * 128 + wm * 64 + mi * 16 + lg * 4 + r;
          int i = rg >> 3, bb = rg & 7;
          dst[((size_t)(bb * 16 + h) * 1024 + i) * 64 + d] = f2bf(acc[mi][ni][r]);
        }
      }
  } else {
#pragma unroll
    for (int mi = 0; mi < 4; ++mi)
#pragma unroll
      for (int ni = 0; ni < 4; ++ni) {
        int c = bn * 128 + wn * 64 + ni * 16 + l15;
#pragma unroll
        for (int r = 0; r < 4; ++r) {
          int rg = bm * 128 + wm * 64 + mi * 16 + lg * 4 + r;
          size_t off = (size_t)rg * 1024 + c;
          yout[off] = resid[off] + acc[mi][ni][r];
        }
      }
  }
}

// ---------------- ck[b,n,j] = r_w_bias[n] . k[b,n,j,:] ----------------
__global__ void ck_k(const u16* __restrict__ kb, const float* __restrict__ rwb,
                     float* __restrict__ ck) {
  int idx = blockIdx.x * 256 + threadIdx.x;  // (b*16+n)*1024 + j
  int n = (idx >> 10) & 15;
  const u16* kr = kb + (size_t)idx * 64;
  const float* wb = rwb + n * 64;
  float s = 0.f;
#pragma unroll
  for (int d0 = 0; d0 < 64; d0 += 8) {
    bf16x8 kv = *(const bf16x8*)(kr + d0);
#pragma unroll
    for (int e = 0; e < 8; ++e) s += bf2f((u16)kv[e]) * wb[d0 + e];
  }
  ck[idx] = s;
}

// ---------------- fused causal rel-attention (flash style) ----------------
// Block: 64 q-rows (4 waves x 16 rows), KV tiles of 64.
// score = 0.125*( (K.Q)^T + ck[j] + q_i.r_emb[j-i+1023] + r_bias[j-i+1023] )
__global__ __launch_bounds__(256) void attn_k(
    const u16* __restrict__ qb, const u16* __restrict__ kb, const u16* __restrict__ vb,
    const u16* __restrict__ remb, const float* __restrict__ rbias,
    const float* __restrict__ ck, u16* __restrict__ av) {
  __shared__ __attribute__((aligned(16))) u16 Klds[64 * 64];
  __shared__ __attribute__((aligned(16))) u16 Vt[64 * 64];  // transposed [d][j]
  __shared__ float Elds[4][16][80];
  __shared__ float rb[1104];

  const int tid = threadIdx.x;
  const int wid = tid >> 6, l = tid & 63;
  const int l15 = l & 15, lg = l >> 4;
  const int b = blockIdx.z, n = blockIdx.y, ib = blockIdx.x * 64;
  const int iw = ib + wid * 16;
  const int bn = b * 16 + n;

  for (int idx = tid; idx < 1104; idx += 256)
    rb[idx] = (idx < 1024) ? rbias[idx * 16 + n] : 0.f;

  const u16* qrow = qb + ((size_t)bn * 1024 + iw + l15) * 64;
  bf16x8 qf0 = *(const bf16x8*)(qrow + lg * 8);       // B-frag: col i=l15, k=d
  bf16x8 qf1 = *(const bf16x8*)(qrow + 32 + lg * 8);

  f32x4 oacc[4] = {};
  float m_run = -1e30f, l_run = 0.f;

  const size_t kvbase = (size_t)bn * 1024 * 64;
  const float* ckp = ck + (size_t)bn * 1024;
  const int njt = ib / 64 + 1;

  for (int jt = 0; jt < njt; ++jt) {
    const int jb = jt * 64;
    __syncthreads();  // previous tile's readers done
    // stage K tile [64][64] (row-major) via global_load_lds
#pragma unroll
    for (int c = 0; c < 2; ++c) {
      int rr = (wid * 2 + c) * 8 + (l >> 3);
      const char* src = (const char*)(kb + kvbase + (size_t)(jb + rr) * 64) + (l & 7) * 16;
      char* dst = (char*)Klds + (wid * 2 + c) * 1024;
      gload16(src, dst);
    }
    // stage V transposed
#pragma unroll
    for (int c = 0; c < 2; ++c) {
      int chunk = tid + c * 256;
      int j = chunk >> 3, d0 = (chunk & 7) * 8;
      bf16x8 vv = *(const bf16x8*)(vb + kvbase + (size_t)(jb + j) * 64 + d0);
#pragma unroll
      for (int e = 0; e < 8; ++e) Vt[(d0 + e) * 64 + j] = (u16)vv[e];
    }
    __syncthreads();

    // E[i,t] = q_i . r_emb[t] for t in [tb, tb+80), rb folded in
    const int tb = jb - iw + 1008;
#pragma unroll
    for (int f = 0; f < 5; ++f) {
      int t = tb + f * 16 + l15;
      int tc = t > 1023 ? 1023 : t;  // >1023 is masked region anyway
      const u16* rr = remb + ((size_t)n * 1024 + tc) * 64;
      bf16x8 ra0 = *(const bf16x8*)(rr + lg * 8);
      bf16x8 ra1 = *(const bf16x8*)(rr + 32 + lg * 8);
      f32x4 et = {};
      et = __builtin_amdgcn_mfma_f32_16x16x32_bf16(ra0, qf0, et, 0, 0, 0);
      et = __builtin_amdgcn_mfma_f32_16x16x32_bf16(ra1, qf1, et, 0, 0, 0);
#pragma unroll
      for (int r2 = 0; r2 < 4; ++r2) {
        int tw = f * 16 + lg * 4 + r2;
        Elds[wid][l15][tw] = et[r2] + rb[tb + tw];
      }
    }

    // S^T = K.Q : acc row j=lg*4+r, col i=l15
    f32x4 st[4];
#pragma unroll
    for (int jj = 0; jj < 4; ++jj) {
      const u16* kr = Klds + (jj * 16 + l15) * 64;
      bf16x8 kf0 = *(const bf16x8*)(kr + lg * 8);
      bf16x8 kf1 = *(const bf16x8*)(kr + 32 + lg * 8);
      f32x4 a = {};
      a = __builtin_amdgcn_mfma_f32_16x16x32_bf16(kf0, qf0, a, 0, 0, 0);
      a = __builtin_amdgcn_mfma_f32_16x16x32_bf16(kf1, qf1, a, 0, 0, 0);
      st[jj] = a;
    }

    const bool domask = (jb == ib);  // only the last tile straddles the diagonal
    float sc[4][4];
    float tmax = -1e30f;
#pragma unroll
    for (int jj = 0; jj < 4; ++jj)
#pragma unroll
      for (int r2 = 0; r2 < 4; ++r2) {
        int jl = jj * 16 + lg * 4 + r2;
        float v = st[jj][r2] + ckp[jb + jl] + Elds[wid][l15][jl - l15 + 15];
        v *= 0.125f;
        if (domask && (jl > wid * 16 + l15)) v = -1e30f;
        sc[jj][r2] = v;
        tmax = fmaxf(tmax, v);
      }
    tmax = fmaxf(tmax, __shfl_xor(tmax, 16));
    tmax = fmaxf(tmax, __shfl_xor(tmax, 32));
    float m_new = fmaxf(m_run, tmax);
    float psum = 0.f;
    bf16x4 pa[4];
#pragma unroll
    for (int jj = 0; jj < 4; ++jj)
#pragma unroll
      for (int r2 = 0; r2 < 4; ++r2) {
        float p = __expf(sc[jj][r2] - m_new);
        psum += p;
        pa[jj][r2] = (short)f2bf(p);
      }
    psum += __shfl_xor(psum, 16);
    psum += __shfl_xor(psum, 32);
    float fac = __expf(m_run - m_new);
    l_run = l_run * fac + psum;
    m_run = m_new;
    float fo[4];
#pragma unroll
    for (int r2 = 0; r2 < 4; ++r2) fo[r2] = __shfl(fac, (l & 48) | (lg * 4 + r2));
#pragma unroll
    for (int dd = 0; dd < 4; ++dd)
#pragma unroll
      for (int r2 = 0; r2 < 4; ++r2) oacc[dd][r2] *= fo[r2];
    // PV: P (in S^T-acc layout) is exactly the 16x16x16 A-fragment
#pragma unroll
    for (int jj = 0; jj < 4; ++jj)
#pragma unroll
      for (int dd = 0; dd < 4; ++dd) {
        bf16x4 vf = *(const bf16x4*)(Vt + (dd * 16 + l15) * 64 + jj * 16 + lg * 4);
        oacc[dd] = __builtin_amdgcn_mfma_f32_16x16x16bf16_1k(pa[jj], vf, oacc[dd], 0, 0, 0);
      }
  }

  float linv = 1.f / l_run;
  float io[4];
#pragma unroll
  for (int r2 = 0; r2 < 4; ++r2) io[r2] = __shfl(linv, (l & 48) | (lg * 4 + r2));
#pragma unroll
  for (int dd = 0; dd < 4; ++dd)
#pragma unroll
    for (int r2 = 0; r2 < 4; ++r2) {
      int ig = iw + lg * 4 + r2;
      av[((size_t)ig * 8 + b) * 1024 + n * 64 + dd * 16 + l15] = f2bf(oacc[dd][r2] * io[r2]);
    }
}

// ---------------- in-place LayerNorm over rows of 1024 ----------------
__global__ void ln_k(float* __restrict__ y, const float* __restrict__ g,
                     const float* __restrict__ be) {
  const int row = blockIdx.x, tid = threadIdx.x;
  float* p = y + (size_t)row * 1024;
  float4 v = ((const float4*)p)[tid];
  float s1 = v.x + v.y + v.z + v.w;
  float s2 = v.x * v.x + v.y * v.y + v.z * v.z + v.w * v.w;
#pragma unroll
  for (int mk = 1; mk < 64; mk <<= 1) {
    s1 += __shfl_xor(s1, mk);
    s2 += __shfl_xor(s2, mk);
  }
  __shared__ float as1[4], as2[4];
  if ((tid & 63) == 0) { as1[tid >> 6] = s1; as2[tid >> 6] = s2; }
  __syncthreads();
  s1 = as1[0] + as1[1] + as1[2] + as1[3];
  s2 = as2[0] + as2[1] + as2[2] + as2[3];
  float mu = s1 * (1.f / 1024.f);
  float var = s2 * (1.f / 1024.f) - mu * mu;
  float rs = rsqrtf(var + 1e-5f);
  float4 gg = ((const float4*)g)[tid];
  float4 bb = ((const float4*)be)[tid];
  float4 o;
  o.x = (v.x - mu) * rs * gg.x + bb.x;
  o.y = (v.y - mu) * rs * gg.y + bb.y;
  o.z = (v.z - mu) * rs * gg.z + bb.z;
  o.w = (v.w - mu) * rs * gg.w + bb.w;
  ((float4*)p)[tid] = o;
}

extern "C" void kernel_launch(void* const* d_in, const int* in_sizes, int n_in,
                              void* d_out, int out_size, void* d_ws, size_t ws_size,
                              hipStream_t stream) {
  (void)in_sizes; (void)n_in; (void)out_size; (void)ws_size;
  const float* w      = (const float*)d_in[0];
  const float* r_emb  = (const float*)d_in[1];
  const float* r_wb   = (const float*)d_in[2];
  const float* r_bias = (const float*)d_in[3];
  const float* qkv_w  = (const float*)d_in[4];
  const float* o_w    = (const float*)d_in[5];
  const float* ln_g   = (const float*)d_in[6];
  const float* ln_b   = (const float*)d_in[7];
  float* out = (float*)d_out;
  char* ws = (char*)d_ws;

  // workspace layout (bytes); total 78,118,912
  u16* w_b    = (u16*)(ws + 0);          // 16 MB; reused as attn_vec after QKV GEMM
  u16* qkvw_t = (u16*)(ws + 16777216);   // 6 MB  [3072][1024]
  u16* ow_t   = (u16*)(ws + 23068672);   // 2 MB  [1024][1024]
  u16* remb_t = (u16*)(ws + 25165824);   // 2 MB  [n][j][d]
  u16* q_b    = (u16*)(ws + 27262976);   // 16 MB [b][h][i][d]
  u16* k_b    = (u16*)(ws + 44040192);   // 16 MB
  u16* v_b    = (u16*)(ws + 60817408);   // 16 MB
  float* ckb  = (float*)(ws + 77594624); // 0.5 MB [b][h][j]
  u16* av_b   = w_b;

  cast_w_k<<<8192, 256, 0, stream>>>(w, w_b);
  transpose_cast_k<<<dim3(96, 32), 256, 0, stream>>>(qkv_w, qkvw_t, 1024, 3072);
  transpose_cast_k<<<dim3(32, 32), 256, 0, stream>>>(o_w, ow_t, 1024, 1024);
  cast_remb_k<<<512, 256, 0, stream>>>(r_emb, remb_t);
  gemm_bt<0><<<dim3(24, 64), 256, 0, stream>>>(w_b, qkvw_t, 1024, q_b, k_b, v_b, nullptr, nullptr);
  ck_k<<<512, 256, 0, stream>>>(k_b, r_wb, ckb);
  attn_k<<<dim3(16, 16, 8), 256, 0, stream>>>(q_b, k_b, v_b, remb_t, r_bias, ckb, av_b);
  gemm_bt<1><<<dim3(8, 64), 256, 0, stream>>>(av_b, ow_t, 1024, nullptr, nullptr, nullptr, w, out);
  ln_k<<<8192, 256, 0, stream>>>(out, ln_g, ln_b);
}

// Round 2
// 289.791 us; speedup vs baseline: 1.9674x; 1.9674x over previous
//
#include <hip/hip_runtime.h>

typedef unsigned short u16;
typedef __attribute__((ext_vector_type(8))) short bf16x8;
typedef __attribute__((ext_vector_type(4))) short bf16x4;
typedef __attribute__((ext_vector_type(4))) float f32x4;
typedef __attribute__((ext_vector_type(4))) unsigned short u16x4;

// Problem constants (fixed by the reference)
#define SEQ 1024
#define BSZ 8
#define NHD 16
#define DHD 64
#define DMODEL 1024

__device__ __forceinline__ u16 f2bf(float x) {
  unsigned u = __float_as_uint(x);
  return (u16)((u + 0x7fffu + ((u >> 16) & 1u)) >> 16);  // RNE
}
__device__ __forceinline__ float bf2f(u16 h) {
  return __uint_as_float(((unsigned)h) << 16);
}

typedef const __attribute__((address_space(1))) unsigned int gu32_t;
typedef __attribute__((address_space(3))) unsigned int lu32_t;
__device__ __forceinline__ void gload16(const void* g, void* l) {
  __builtin_amdgcn_global_load_lds((gu32_t*)g, (lu32_t*)l, 16, 0, 0);
}

// ---------------- cast / transpose kernels ----------------
__global__ void cast_w_k(const float* __restrict__ in, u16* __restrict__ out) {
  size_t i = ((size_t)blockIdx.x * 256 + threadIdx.x) * 4;
  float4 v = *(const float4*)(in + i);
  u16x4 o;
  o[0] = f2bf(v.x); o[1] = f2bf(v.y); o[2] = f2bf(v.z); o[3] = f2bf(v.w);
  *(u16x4*)(out + i) = o;
}

// in [R][C] f32 -> out [C][R] bf16
__global__ void transpose_cast_k(const float* __restrict__ in, u16* __restrict__ out,
                                 int R, int C) {
  __shared__ float tile[32][33];
  int tx = threadIdx.x & 31, ty = threadIdx.x >> 5;
  int bx = blockIdx.x * 32, by = blockIdx.y * 32;
#pragma unroll
  for (int rr = ty; rr < 32; rr += 8)
    tile[rr][tx] = in[(size_t)(by + rr) * C + bx + tx];
  __syncthreads();
#pragma unroll
  for (int rr = ty; rr < 32; rr += 8)
    out[(size_t)(bx + rr) * R + by + tx] = f2bf(tile[tx][rr]);
}

// r_emb [j][n][d] f32 -> [n][j][d] bf16
__global__ void cast_remb_k(const float* __restrict__ in, u16* __restrict__ out) {
  int t = blockIdx.x * 256 + threadIdx.x;  // (j*16+n)*8 + db
  int jn = t >> 3, db = t & 7;
  int j = jn >> 4, n = jn & 15;
  const float* src = in + (size_t)jn * 64 + db * 8;
  u16* dst = out + ((size_t)(n * 1024 + j)) * 64 + db * 8;
#pragma unroll
  for (int e = 0; e < 8; ++e) dst[e] = f2bf(src[e]);
}

// ---------------- GEMM: C[M,N] = A[M,K] @ Bt[N,K]^T  (bf16, 128x128 tile) ----------------
// EPI 0: scatter into q[b][h][i][d], k[b][h][j][d], v TRANSPOSED [b][h][d][j] (bf16).
// EPI 1: yout = resid + C (f32).
template <int EPI>
__global__ __launch_bounds__(256) void gemm_bt(
    const u16* __restrict__ A, const u16* __restrict__ Bt, int K,
    u16* __restrict__ q_o, u16* __restrict__ k_o, u16* __restrict__ v_o,
    const float* __restrict__ resid, float* __restrict__ yout) {
  __shared__ __attribute__((aligned(16))) u16 ldsA[2][4096];  // [128 rows][32 k]
  __shared__ __attribute__((aligned(16))) u16 ldsB[2][4096];
  const int tid = threadIdx.x;
  const int wid = tid >> 6, l = tid & 63;
  const int l15 = l & 15, lg = l >> 4;
  const int bm = blockIdx.y, bn = blockIdx.x;
  const int wm = wid & 1, wn = wid >> 1;
  const size_t ldb = (size_t)K * 2;  // row bytes

  const char* aA = (const char*)A + (size_t)(bm * 128 + wid * 32 + (l >> 2)) * ldb + (l & 3) * 16;
  const char* aB = (const char*)Bt + (size_t)(bn * 128 + wid * 32 + (l >> 2)) * ldb + (l & 3) * 16;

  auto stage = [&](int buf, int kt) {
    const char* sa = aA + (size_t)kt * 64;
    const char* sb = aB + (size_t)kt * 64;
    char* la = (char*)&ldsA[buf][wid * 1024];
    char* lb = (char*)&ldsB[buf][wid * 1024];
    gload16(sa, la);
    gload16(sa + 16 * ldb, la + 1024);
    gload16(sb, lb);
    gload16(sb + 16 * ldb, lb + 1024);
  };

  f32x4 acc[4][4] = {};
  stage(0, 0);
  __syncthreads();
  const int NT = K >> 5;
  for (int t = 0; t < NT; ++t) {
    int cur = t & 1;
    if (t + 1 < NT) stage(cur ^ 1, t + 1);
    bf16x8 af[4], bfr[4];
#pragma unroll
    for (int mi = 0; mi < 4; ++mi)
      af[mi] = *(const bf16x8*)&ldsA[cur][(wm * 64 + mi * 16 + l15) * 32 + lg * 8];
#pragma unroll
    for (int ni = 0; ni < 4; ++ni)
      bfr[ni] = *(const bf16x8*)&ldsB[cur][(wn * 64 + ni * 16 + l15) * 32 + lg * 8];
#pragma unroll
    for (int mi = 0; mi < 4; ++mi)
#pragma unroll
      for (int ni = 0; ni < 4; ++ni)
        acc[mi][ni] = __builtin_amdgcn_mfma_f32_16x16x32_bf16(af[mi], bfr[ni], acc[mi][ni], 0, 0, 0);
    __syncthreads();
  }

  if (EPI == 0) {
#pragma unroll
    for (int mi = 0; mi < 4; ++mi)
#pragma unroll
      for (int ni = 0; ni < 4; ++ni) {
        int c = bn * 128 + wn * 64 + ni * 16 + l15;
        int which = c >> 10, rem = c & 1023, h = rem >> 6, d = rem & 63;
        u16* dst = which == 0 ? q_o : (which == 1 ? k_o : v_o);
#pragma unroll
        for (int r = 0; r < 4; ++r) {
          int rg = bm * 128 + wm * 64 + mi * 16 + lg * 4 + r;
          int i = rg >> 3, bb = rg & 7;
          size_t idx = (which == 2)
              ? ((size_t)(bb * 16 + h) * 64 + d) * 1024 + i       // V^T [b][h][d][j]
              : ((size_t)(bb * 16 + h) * 1024 + i) * 64 + d;      // Q,K [b][h][i][d]
          dst[idx] = f2bf(acc[mi][ni][r]);
        }
      }
  } else {
#pragma unroll
    for (int mi = 0; mi < 4; ++mi)
#pragma unroll
      for (int ni = 0; ni < 4; ++ni) {
        int c = bn * 128 + wn * 64 + ni * 16 + l15;
#pragma unroll
        for (int r = 0; r < 4; ++r) {
          int rg = bm * 128 + wm * 64 + mi * 16 + lg * 4 + r;
          size_t off = (size_t)rg * 1024 + c;
          yout[off] = resid[off] + acc[mi][ni][r];
        }
      }
  }
}

// ---------------- ck[b,n,j] = r_w_bias[n] . k[b,n,j,:] ----------------
__global__ void ck_k(const u16* __restrict__ kb, const float* __restrict__ rwb,
                     float* __restrict__ ck) {
  int idx = blockIdx.x * 256 + threadIdx.x;  // (b*16+n)*1024 + j
  int n = (idx >> 10) & 15;
  const u16* kr = kb + (size_t)idx * 64;
  const float* wb = rwb + n * 64;
  float s = 0.f;
#pragma unroll
  for (int d0 = 0; d0 < 64; d0 += 8) {
    bf16x8 kv = *(const bf16x8*)(kr + d0);
#pragma unroll
    for (int e = 0; e < 8; ++e) s += bf2f((u16)kv[e]) * wb[d0 + e];
  }
  ck[idx] = s;
}

// ---------------- fused causal rel-attention (flash style) ----------------
// Block: 64 q-rows (4 waves x 16 rows), KV tiles of 64. Longest blocks first.
// score = 0.125*( (K.Q)^T + ck[j] + q_i.r_emb[j-i+1023] + r_bias[j-i+1023] )
// K and V^T tiles staged via global_load_lds with XOR-swizzled SOURCE chunks
// (chunk ^= row&7 at 16B granularity); reads apply the same XOR -> no 16-way
// bank conflicts (G4 fix, both-sides-or-neither per rule #21).
__global__ __launch_bounds__(256, 5) void attn_k(
    const u16* __restrict__ qg, const u16* __restrict__ kb, const u16* __restrict__ vtb,
    const u16* __restrict__ remb, const float* __restrict__ rbias,
    const float* __restrict__ ck, u16* __restrict__ av) {
  __shared__ __attribute__((aligned(16))) u16 Klds[64 * 64];
  __shared__ __attribute__((aligned(16))) u16 Vlds[64 * 64];  // V^T [d][j], swizzled
  __shared__ u16 Elds[4][16][84];   // bf16 E+rb, padded stride 84
  __shared__ float rb[1088];

  const int tid = threadIdx.x;
  const int wid = tid >> 6, l = tid & 63;
  const int l15 = l & 15, lg = l >> 4;
  const int id = blockIdx.x;
  const int qblk = 15 - (id >> 7);   // longest-first dispatch
  const int bn = id & 127;
  const int b = bn >> 4, n = bn & 15;
  const int ib = qblk * 64;
  const int iw = ib + wid * 16;

  for (int idx = tid; idx < 1088; idx += 256)
    rb[idx] = (idx < 1024) ? rbias[idx * 16 + n] : 0.f;

  const u16* qrow = qg + ((size_t)bn * 1024 + iw + l15) * 64;
  bf16x8 qf0 = *(const bf16x8*)(qrow + lg * 8);       // B-frag: col i=l15, k=d
  bf16x8 qf1 = *(const bf16x8*)(qrow + 32 + lg * 8);

  f32x4 oacc[4] = {};
  float m_run = -1e30f, l_run = 0.f;

  const size_t kvbase = (size_t)bn * (1024 * 64);
  const float* ckp = ck + (size_t)bn * 1024;
  const int njt = qblk + 1;

  const int srow = l >> 3;               // row within 8-row staging group
  const int schunk = (l & 7) ^ srow;     // pre-swizzled source 16B chunk
  const int x7 = l15 & 7;

  for (int jt = 0; jt < njt; ++jt) {
    const int jb = jt * 64;
    __syncthreads();  // previous tile's readers done
#pragma unroll
    for (int c = 0; c < 2; ++c) {
      int r8 = (wid * 2 + c) * 8;
      // K tile rows = j (64 d contiguous)
      const char* srck = (const char*)(kb + kvbase + (size_t)(jb + r8 + srow) * 64) + schunk * 16;
      gload16(srck, (char*)Klds + (wid * 2 + c) * 1024);
      // V^T tile rows = d (j contiguous)
      const char* srcv = (const char*)(vtb + kvbase + (size_t)(r8 + srow) * 1024 + jb) + schunk * 16;
      gload16(srcv, (char*)Vlds + (wid * 2 + c) * 1024);
    }
    __syncthreads();

    // E[i,t] = q_i . r_emb[t] for t in [tb, tb+80), rb folded, stored bf16
    const int tb = jb - iw + 1008;
#pragma unroll
    for (int f = 0; f < 5; ++f) {
      int t = tb + f * 16 + l15;
      int tc = t > 1023 ? 1023 : t;  // >1023 is masked region anyway
      const u16* rr = remb + ((size_t)n * 1024 + tc) * 64;
      bf16x8 ra0 = *(const bf16x8*)(rr + lg * 8);
      bf16x8 ra1 = *(const bf16x8*)(rr + 32 + lg * 8);
      f32x4 et = {};
      et = __builtin_amdgcn_mfma_f32_16x16x32_bf16(ra0, qf0, et, 0, 0, 0);
      et = __builtin_amdgcn_mfma_f32_16x16x32_bf16(ra1, qf1, et, 0, 0, 0);
#pragma unroll
      for (int r2 = 0; r2 < 4; ++r2) {
        int tw = f * 16 + lg * 4 + r2;
        Elds[wid][l15][tw] = f2bf(et[r2] + rb[tb + tw]);
      }
    }

    // S^T = K.Q : acc row j=lg*4+r, col i=l15 (swizzled K reads)
    f32x4 st[4];
#pragma unroll
    for (int jj = 0; jj < 4; ++jj) {
      const u16* kr = Klds + (jj * 16 + l15) * 64;
      bf16x8 kf0 = *(const bf16x8*)(kr + ((lg ^ x7) << 3));
      bf16x8 kf1 = *(const bf16x8*)(kr + (((lg + 4) ^ x7) << 3));
      f32x4 a = {};
      a = __builtin_amdgcn_mfma_f32_16x16x32_bf16(kf0, qf0, a, 0, 0, 0);
      a = __builtin_amdgcn_mfma_f32_16x16x32_bf16(kf1, qf1, a, 0, 0, 0);
      st[jj] = a;
    }

    const bool domask = (jb == ib);  // only the diagonal tile needs masking
    float sc[4][4];
    float tmax = -1e30f;
#pragma unroll
    for (int jj = 0; jj < 4; ++jj)
#pragma unroll
      for (int r2 = 0; r2 < 4; ++r2) {
        int jl = jj * 16 + lg * 4 + r2;
        float v = st[jj][r2] + ckp[jb + jl] + bf2f(Elds[wid][l15][jl - l15 + 15]);
        v *= 0.125f;
        if (domask && (jl > wid * 16 + l15)) v = -1e30f;
        sc[jj][r2] = v;
        tmax = fmaxf(tmax, v);
      }
    tmax = fmaxf(tmax, __shfl_xor(tmax, 16));
    tmax = fmaxf(tmax, __shfl_xor(tmax, 32));
    float m_new = fmaxf(m_run, tmax);
    float psum = 0.f;
    bf16x4 pa[4];
#pragma unroll
    for (int jj = 0; jj < 4; ++jj)
#pragma unroll
      for (int r2 = 0; r2 < 4; ++r2) {
        float p = __expf(sc[jj][r2] - m_new);
        psum += p;
        pa[jj][r2] = (short)f2bf(p);
      }
    psum += __shfl_xor(psum, 16);
    psum += __shfl_xor(psum, 32);
    float fac = __expf(m_run - m_new);
    l_run = l_run * fac + psum;
    m_run = m_new;
    float fo[4];
#pragma unroll
    for (int r2 = 0; r2 < 4; ++r2) fo[r2] = __shfl(fac, (l & 48) | (lg * 4 + r2));
#pragma unroll
    for (int dd = 0; dd < 4; ++dd)
#pragma unroll
      for (int r2 = 0; r2 < 4; ++r2) oacc[dd][r2] *= fo[r2];
    // PV: P (in S^T-acc layout) is exactly the 16x16x16 A-fragment
#pragma unroll
    for (int jj = 0; jj < 4; ++jj)
#pragma unroll
      for (int dd = 0; dd < 4; ++dd) {
        int vchunk = (jj * 2 + (lg >> 1)) ^ x7;
        const u16* vp = Vlds + (dd * 16 + l15) * 64 + (vchunk << 3) + (lg & 1) * 4;
        bf16x4 vf = *(const bf16x4*)vp;
        oacc[dd] = __builtin_amdgcn_mfma_f32_16x16x16bf16_1k(pa[jj], vf, oacc[dd], 0, 0, 0);
      }
  }

  float linv = 1.f / l_run;
  float io[4];
#pragma unroll
  for (int r2 = 0; r2 < 4; ++r2) io[r2] = __shfl(linv, (l & 48) | (lg * 4 + r2));
#pragma unroll
  for (int dd = 0; dd < 4; ++dd)
#pragma unroll
    for (int r2 = 0; r2 < 4; ++r2) {
      int ig = iw + lg * 4 + r2;
      av[((size_t)ig * 8 + b) * 1024 + n * 64 + dd * 16 + l15] = f2bf(oacc[dd][r2] * io[r2]);
    }
}

// ---------------- in-place LayerNorm over rows of 1024 ----------------
__global__ void ln_k(float* __restrict__ y, const float* __restrict__ g,
                     const float* __restrict__ be) {
  const int row = blockIdx.x, tid = threadIdx.x;
  float* p = y + (size_t)row * 1024;
  float4 v = ((const float4*)p)[tid];
  float s1 = v.x + v.y + v.z + v.w;
  float s2 = v.x * v.x + v.y * v.y + v.z * v.z + v.w * v.w;
#pragma unroll
  for (int mk = 1; mk < 64; mk <<= 1) {
    s1 += __shfl_xor(s1, mk);
    s2 += __shfl_xor(s2, mk);
  }
  __shared__ float as1[4], as2[4];
  if ((tid & 63) == 0) { as1[tid >> 6] = s1; as2[tid >> 6] = s2; }
  __syncthreads();
  s1 = as1[0] + as1[1] + as1[2] + as1[3];
  s2 = as2[0] + as2[1] + as2[2] + as2[3];
  float mu = s1 * (1.f / 1024.f);
  float var = s2 * (1.f / 1024.f) - mu * mu;
  float rs = rsqrtf(var + 1e-5f);
  float4 gg = ((const float4*)g)[tid];
  float4 bb = ((const float4*)be)[tid];
  float4 o;
  o.x = (v.x - mu) * rs * gg.x + bb.x;
  o.y = (v.y - mu) * rs * gg.y + bb.y;
  o.z = (v.z - mu) * rs * gg.z + bb.z;
  o.w = (v.w - mu) * rs * gg.w + bb.w;
  ((float4*)p)[tid] = o;
}

extern "C" void kernel_launch(void* const* d_in, const int* in_sizes, int n_in,
                              void* d_out, int out_size, void* d_ws, size_t ws_size,
                              hipStream_t stream) {
  (void)in_sizes; (void)n_in; (void)out_size; (void)ws_size;
  const float* w      = (const float*)d_in[0];
  const float* r_emb  = (const float*)d_in[1];
  const float* r_wb   = (const float*)d_in[2];
  const float* r_bias = (const float*)d_in[3];
  const float* qkv_w  = (const float*)d_in[4];
  const float* o_w    = (const float*)d_in[5];
  const float* ln_g   = (const float*)d_in[6];
  const float* ln_b   = (const float*)d_in[7];
  float* out = (float*)d_out;
  char* ws = (char*)d_ws;

  // workspace layout (bytes); total 78,118,912
  u16* w_b    = (u16*)(ws + 0);          // 16 MB; reused as attn_vec after QKV GEMM
  u16* qkvw_t = (u16*)(ws + 16777216);   // 6 MB  [3072][1024]
  u16* ow_t   = (u16*)(ws + 23068672);   // 2 MB  [1024][1024]
  u16* remb_t = (u16*)(ws + 25165824);   // 2 MB  [n][j][d]
  u16* q_b    = (u16*)(ws + 27262976);   // 16 MB [b][h][i][d]
  u16* k_b    = (u16*)(ws + 44040192);   // 16 MB [b][h][j][d]
  u16* vt_b   = (u16*)(ws + 60817408);   // 16 MB [b][h][d][j]  (transposed!)
  float* ckb  = (float*)(ws + 77594624); // 0.5 MB [b][h][j]
  u16* av_b   = w_b;

  cast_w_k<<<8192, 256, 0, stream>>>(w, w_b);
  transpose_cast_k<<<dim3(96, 32), 256, 0, stream>>>(qkv_w, qkvw_t, 1024, 3072);
  transpose_cast_k<<<dim3(32, 32), 256, 0, stream>>>(o_w, ow_t, 1024, 1024);
  cast_remb_k<<<512, 256, 0, stream>>>(r_emb, remb_t);
  gemm_bt<0><<<dim3(24, 64), 256, 0, stream>>>(w_b, qkvw_t, 1024, q_b, k_b, vt_b, nullptr, nullptr);
  ck_k<<<512, 256, 0, stream>>>(k_b, r_wb, ckb);
  attn_k<<<dim3(2048), 256, 0, stream>>>(q_b, k_b, vt_b, remb_t, r_bias, ckb, av_b);
  gemm_bt<1><<<dim3(8, 64), 256, 0, stream>>>(av_b, ow_t, 1024, nullptr, nullptr, nullptr, w, out);
  ln_k<<<8192, 256, 0, stream>>>(out, ln_g, ln_b);
}

// Round 3
// 266.357 us; speedup vs baseline: 2.1405x; 1.0880x over previous
//
#include <hip/hip_runtime.h>

typedef unsigned short u16;
typedef __attribute__((ext_vector_type(8))) short bf16x8;
typedef __attribute__((ext_vector_type(4))) short bf16x4;
typedef __attribute__((ext_vector_type(4))) float f32x4;
typedef __attribute__((ext_vector_type(4))) unsigned short u16x4;

// Problem constants (fixed by the reference)
#define SEQ 1024
#define BSZ 8
#define NHD 16
#define DHD 64
#define DMODEL 1024

__device__ __forceinline__ u16 f2bf(float x) {
  unsigned u = __float_as_uint(x);
  return (u16)((u + 0x7fffu + ((u >> 16) & 1u)) >> 16);  // RNE
}
__device__ __forceinline__ float bf2f(u16 h) {
  return __uint_as_float(((unsigned)h) << 16);
}

typedef const __attribute__((address_space(1))) unsigned int gu32_t;
typedef __attribute__((address_space(3))) unsigned int lu32_t;
__device__ __forceinline__ void gload16(const void* g, void* l) {
  __builtin_amdgcn_global_load_lds((gu32_t*)g, (lu32_t*)l, 16, 0, 0);
}

// ---------------- cast / transpose kernels ----------------
__global__ void cast_w_k(const float* __restrict__ in, u16* __restrict__ out) {
  size_t i = ((size_t)blockIdx.x * 256 + threadIdx.x) * 4;
  float4 v = *(const float4*)(in + i);
  u16x4 o;
  o[0] = f2bf(v.x); o[1] = f2bf(v.y); o[2] = f2bf(v.z); o[3] = f2bf(v.w);
  *(u16x4*)(out + i) = o;
}

// in [R][C] f32 -> out [C][R] bf16
__global__ void transpose_cast_k(const float* __restrict__ in, u16* __restrict__ out,
                                 int R, int C) {
  __shared__ float tile[32][33];
  int tx = threadIdx.x & 31, ty = threadIdx.x >> 5;
  int bx = blockIdx.x * 32, by = blockIdx.y * 32;
#pragma unroll
  for (int rr = ty; rr < 32; rr += 8)
    tile[rr][tx] = in[(size_t)(by + rr) * C + bx + tx];
  __syncthreads();
#pragma unroll
  for (int rr = ty; rr < 32; rr += 8)
    out[(size_t)(bx + rr) * R + by + tx] = f2bf(tile[tx][rr]);
}

// r_emb [j][n][d] f32 -> [n][j][d] bf16
__global__ void cast_remb_k(const float* __restrict__ in, u16* __restrict__ out) {
  int t = blockIdx.x * 256 + threadIdx.x;  // (j*16+n)*8 + db
  int jn = t >> 3, db = t & 7;
  int j = jn >> 4, n = jn & 15;
  const float* src = in + (size_t)jn * 64 + db * 8;
  u16* dst = out + ((size_t)(n * 1024 + j)) * 64 + db * 8;
#pragma unroll
  for (int e = 0; e < 8; ++e) dst[e] = f2bf(src[e]);
}

// ---------------- GEMM: C[M,N] = A[M,K] @ Bt[N,K]^T  (bf16, 128x128 tile) ----------------
// EPI 0: scatter into q[b][h][i][d], k[b][h][j][d], v TRANSPOSED [b][h][d][j] (bf16).
// EPI 1: yout = resid + C (f32).
template <int EPI>
__global__ __launch_bounds__(256) void gemm_bt(
    const u16* __restrict__ A, const u16* __restrict__ Bt, int K,
    u16* __restrict__ q_o, u16* __restrict__ k_o, u16* __restrict__ v_o,
    const float* __restrict__ resid, float* __restrict__ yout) {
  __shared__ __attribute__((aligned(16))) u16 ldsA[2][4096];  // [128 rows][32 k]
  __shared__ __attribute__((aligned(16))) u16 ldsB[2][4096];
  const int tid = threadIdx.x;
  const int wid = tid >> 6, l = tid & 63;
  const int l15 = l & 15, lg = l >> 4;
  const int bm = blockIdx.y, bn = blockIdx.x;
  const int wm = wid & 1, wn = wid >> 1;
  const size_t ldb = (size_t)K * 2;  // row bytes

  const char* aA = (const char*)A + (size_t)(bm * 128 + wid * 32 + (l >> 2)) * ldb + (l & 3) * 16;
  const char* aB = (const char*)Bt + (size_t)(bn * 128 + wid * 32 + (l >> 2)) * ldb + (l & 3) * 16;

  auto stage = [&](int buf, int kt) {
    const char* sa = aA + (size_t)kt * 64;
    const char* sb = aB + (size_t)kt * 64;
    char* la = (char*)&ldsA[buf][wid * 1024];
    char* lb = (char*)&ldsB[buf][wid * 1024];
    gload16(sa, la);
    gload16(sa + 16 * ldb, la + 1024);
    gload16(sb, lb);
    gload16(sb + 16 * ldb, lb + 1024);
  };

  f32x4 acc[4][4] = {};
  stage(0, 0);
  __syncthreads();
  const int NT = K >> 5;
  for (int t = 0; t < NT; ++t) {
    int cur = t & 1;
    if (t + 1 < NT) stage(cur ^ 1, t + 1);
    bf16x8 af[4], bfr[4];
#pragma unroll
    for (int mi = 0; mi < 4; ++mi)
      af[mi] = *(const bf16x8*)&ldsA[cur][(wm * 64 + mi * 16 + l15) * 32 + lg * 8];
#pragma unroll
    for (int ni = 0; ni < 4; ++ni)
      bfr[ni] = *(const bf16x8*)&ldsB[cur][(wn * 64 + ni * 16 + l15) * 32 + lg * 8];
#pragma unroll
    for (int mi = 0; mi < 4; ++mi)
#pragma unroll
      for (int ni = 0; ni < 4; ++ni)
        acc[mi][ni] = __builtin_amdgcn_mfma_f32_16x16x32_bf16(af[mi], bfr[ni], acc[mi][ni], 0, 0, 0);
    __syncthreads();
  }

  if (EPI == 0) {
#pragma unroll
    for (int mi = 0; mi < 4; ++mi)
#pragma unroll
      for (int ni = 0; ni < 4; ++ni) {
        int c = bn * 128 + wn * 64 + ni * 16 + l15;
        int which = c >> 10, rem = c & 1023, h = rem >> 6, d = rem & 63;
        u16* dst = which == 0 ? q_o : (which == 1 ? k_o : v_o);
#pragma unroll
        for (int r = 0; r < 4; ++r) {
          int rg = bm * 128 + wm * 64 + mi * 16 + lg * 4 + r;
          int i = rg >> 3, bb = rg & 7;
          size_t idx = (which == 2)
              ? ((size_t)(bb * 16 + h) * 64 + d) * 1024 + i       // V^T [b][h][d][j]
              : ((size_t)(bb * 16 + h) * 1024 + i) * 64 + d;      // Q,K [b][h][i][d]
          dst[idx] = f2bf(acc[mi][ni][r]);
        }
      }
  } else {
#pragma unroll
    for (int mi = 0; mi < 4; ++mi)
#pragma unroll
      for (int ni = 0; ni < 4; ++ni) {
        int c = bn * 128 + wn * 64 + ni * 16 + l15;
#pragma unroll
        for (int r = 0; r < 4; ++r) {
          int rg = bm * 128 + wm * 64 + mi * 16 + lg * 4 + r;
          size_t off = (size_t)rg * 1024 + c;
          yout[off] = resid[off] + acc[mi][ni][r];
        }
      }
  }
}

// ---------------- fused causal rel-attention (flash style, 2-phase pipelined) ----------------
// Block: 64 q-rows (4 waves x 16 rows), KV tiles of 64, longest blocks first.
// score = 0.125*( (K.(q+rwb))^T + q_i.r_emb[j-i+1023] + r_bias[j-i+1023] )
// K/V^T double-buffered; stage(next) issued BEFORE compute(cur); single barrier
// per tile (its vmcnt(0) drain is the pipeline wait) — T3-minimal 2-phase.
// XOR-swizzled staging (chunk ^= row&7, 16B) with matching swizzled reads.
__global__ __launch_bounds__(256, 3) void attn_k(
    const u16* __restrict__ qg, const u16* __restrict__ kb, const u16* __restrict__ vtb,
    const u16* __restrict__ remb, const float* __restrict__ rbias,
    const float* __restrict__ rwb, u16* __restrict__ av) {
  __shared__ __attribute__((aligned(16))) u16 Klds[2][4096];
  __shared__ __attribute__((aligned(16))) u16 Vlds[2][4096];  // V^T [d][j], swizzled
  __shared__ u16 Elds[4][16][84];   // bf16 E+rb, padded stride 84
  __shared__ float rb[1088];

  const int tid = threadIdx.x;
  const int wid = tid >> 6, l = tid & 63;
  const int l15 = l & 15, lg = l >> 4;
  const int id = blockIdx.x;
  const int qblk = 15 - (id >> 7);   // longest-first dispatch
  const int bn = id & 127;
  const int b = bn >> 4, n = bn & 15;
  const int ib = qblk * 64;
  const int iw = ib + wid * 16;

  for (int idx = tid; idx < 1088; idx += 256)
    rb[idx] = (idx < 1024) ? rbias[idx * 16 + n] : 0.f;

  // Q fragments: plain (for E) and +r_w_bias (for content score)
  const u16* qrow = qg + ((size_t)bn * 1024 + iw + l15) * 64;
  const float* wbp = rwb + n * 64;
  bf16x8 qf0 = *(const bf16x8*)(qrow + lg * 8);       // B-frag: col i=l15, k=d
  bf16x8 qf1 = *(const bf16x8*)(qrow + 32 + lg * 8);
  bf16x8 qw0, qw1;
#pragma unroll
  for (int e = 0; e < 8; ++e) {
    qw0[e] = (short)f2bf(bf2f((u16)qf0[e]) + wbp[lg * 8 + e]);
    qw1[e] = (short)f2bf(bf2f((u16)qf1[e]) + wbp[32 + lg * 8 + e]);
  }

  f32x4 oacc[4] = {};
  float m_run = -1e30f, l_run = 0.f;

  const size_t kvbase = (size_t)bn * (1024 * 64);
  const int njt = qblk + 1;

  const int srow = l >> 3;               // row within 8-row staging group
  const int schunk = (l & 7) ^ srow;     // pre-swizzled source 16B chunk
  const int x7 = l15 & 7;

  auto stage = [&](int buf, int jb2) {
#pragma unroll
    for (int c = 0; c < 2; ++c) {
      int r8 = (wid * 2 + c) * 8;
      const char* srck = (const char*)(kb + kvbase + (size_t)(jb2 + r8 + srow) * 64) + schunk * 16;
      gload16(srck, (char*)&Klds[buf][0] + (wid * 2 + c) * 1024);
      const char* srcv = (const char*)(vtb + kvbase + (size_t)(r8 + srow) * 1024 + jb2) + schunk * 16;
      gload16(srcv, (char*)&Vlds[buf][0] + (wid * 2 + c) * 1024);
    }
  };

  stage(0, 0);
  __syncthreads();  // drains vmcnt(0): tile 0 staged, rb visible

  for (int jt = 0; jt < njt; ++jt) {
    const int jb = jt * 64;
    const int cur = jt & 1;
    if (jt + 1 < njt) stage(cur ^ 1, jb + 64);  // prefetch next tile (async)

    // E[i,t] = q_i . r_emb[t] for t in [tb, tb+80), rb folded, stored bf16
    const int tb = jb - iw + 1008;
#pragma unroll
    for (int f = 0; f < 5; ++f) {
      int t = tb + f * 16 + l15;
      int tc = t > 1023 ? 1023 : t;  // >1023 is masked region anyway
      const u16* rr = remb + ((size_t)n * 1024 + tc) * 64;
      bf16x8 ra0 = *(const bf16x8*)(rr + lg * 8);
      bf16x8 ra1 = *(const bf16x8*)(rr + 32 + lg * 8);
      f32x4 et = {};
      et = __builtin_amdgcn_mfma_f32_16x16x32_bf16(ra0, qf0, et, 0, 0, 0);
      et = __builtin_amdgcn_mfma_f32_16x16x32_bf16(ra1, qf1, et, 0, 0, 0);
#pragma unroll
      for (int r2 = 0; r2 < 4; ++r2) {
        int tw = f * 16 + lg * 4 + r2;
        Elds[wid][l15][tw] = f2bf(et[r2] + rb[tb + tw]);
      }
    }

    // S^T = K.(q+rwb) : acc row j=lg*4+r, col i=l15 (swizzled K reads)
    f32x4 st[4];
    __builtin_amdgcn_s_setprio(1);
#pragma unroll
    for (int jj = 0; jj < 4; ++jj) {
      const u16* kr = &Klds[cur][0] + (jj * 16 + l15) * 64;
      bf16x8 kf0 = *(const bf16x8*)(kr + ((lg ^ x7) << 3));
      bf16x8 kf1 = *(const bf16x8*)(kr + (((lg + 4) ^ x7) << 3));
      f32x4 a = {};
      a = __builtin_amdgcn_mfma_f32_16x16x32_bf16(kf0, qw0, a, 0, 0, 0);
      a = __builtin_amdgcn_mfma_f32_16x16x32_bf16(kf1, qw1, a, 0, 0, 0);
      st[jj] = a;
    }
    __builtin_amdgcn_s_setprio(0);

    const bool domask = (jb == ib);  // only the diagonal tile needs masking
    float sc[4][4];
    float tmax = -1e30f;
#pragma unroll
    for (int jj = 0; jj < 4; ++jj)
#pragma unroll
      for (int r2 = 0; r2 < 4; ++r2) {
        int jl = jj * 16 + lg * 4 + r2;
        float v = st[jj][r2] + bf2f(Elds[wid][l15][jl - l15 + 15]);
        v *= 0.125f;
        if (domask && (jl > wid * 16 + l15)) v = -1e30f;
        sc[jj][r2] = v;
        tmax = fmaxf(tmax, v);
      }
    tmax = fmaxf(tmax, __shfl_xor(tmax, 16));
    tmax = fmaxf(tmax, __shfl_xor(tmax, 32));

    // defer-max (T13): only rescale when the running max grew by > 8
    if (!__all(tmax - m_run <= 8.0f)) {
      float m_new = fmaxf(m_run, tmax);
      float fac = __expf(m_run - m_new);
      m_run = m_new;
      l_run *= fac;
      float fo[4];
#pragma unroll
      for (int r2 = 0; r2 < 4; ++r2) fo[r2] = __shfl(fac, (l & 48) | (lg * 4 + r2));
#pragma unroll
      for (int dd = 0; dd < 4; ++dd)
#pragma unroll
        for (int r2 = 0; r2 < 4; ++r2) oacc[dd][r2] *= fo[r2];
    }

    float psum = 0.f;
    bf16x4 pa[4];
#pragma unroll
    for (int jj = 0; jj < 4; ++jj)
#pragma unroll
      for (int r2 = 0; r2 < 4; ++r2) {
        float p = __expf(sc[jj][r2] - m_run);
        psum += p;
        pa[jj][r2] = (short)f2bf(p);
      }
    psum += __shfl_xor(psum, 16);
    psum += __shfl_xor(psum, 32);
    l_run += psum;

    // PV: P (in S^T-acc layout) is exactly the 16x16x16 A-fragment
    __builtin_amdgcn_s_setprio(1);
#pragma unroll
    for (int jj = 0; jj < 4; ++jj)
#pragma unroll
      for (int dd = 0; dd < 4; ++dd) {
        int vchunk = (jj * 2 + (lg >> 1)) ^ x7;
        const u16* vp = &Vlds[cur][0] + (dd * 16 + l15) * 64 + (vchunk << 3) + (lg & 1) * 4;
        bf16x4 vf = *(const bf16x4*)vp;
        oacc[dd] = __builtin_amdgcn_mfma_f32_16x16x16bf16_1k(pa[jj], vf, oacc[dd], 0, 0, 0);
      }
    __builtin_amdgcn_s_setprio(0);

    __syncthreads();  // one barrier/tile: drains next-tile stage + frees buffers
  }

  float linv = 1.f / l_run;
  float io[4];
#pragma unroll
  for (int r2 = 0; r2 < 4; ++r2) io[r2] = __shfl(linv, (l & 48) | (lg * 4 + r2));
#pragma unroll
  for (int dd = 0; dd < 4; ++dd)
#pragma unroll
    for (int r2 = 0; r2 < 4; ++r2) {
      int ig = iw + lg * 4 + r2;
      av[((size_t)ig * 8 + b) * 1024 + n * 64 + dd * 16 + l15] = f2bf(oacc[dd][r2] * io[r2]);
    }
}

// ---------------- in-place LayerNorm over rows of 1024 ----------------
__global__ void ln_k(float* __restrict__ y, const float* __restrict__ g,
                     const float* __restrict__ be) {
  const int row = blockIdx.x, tid = threadIdx.x;
  float* p = y + (size_t)row * 1024;
  float4 v = ((const float4*)p)[tid];
  float s1 = v.x + v.y + v.z + v.w;
  float s2 = v.x * v.x + v.y * v.y + v.z * v.z + v.w * v.w;
#pragma unroll
  for (int mk = 1; mk < 64; mk <<= 1) {
    s1 += __shfl_xor(s1, mk);
    s2 += __shfl_xor(s2, mk);
  }
  __shared__ float as1[4], as2[4];
  if ((tid & 63) == 0) { as1[tid >> 6] = s1; as2[tid >> 6] = s2; }
  __syncthreads();
  s1 = as1[0] + as1[1] + as1[2] + as1[3];
  s2 = as2[0] + as2[1] + as2[2] + as2[3];
  float mu = s1 * (1.f / 1024.f);
  float var = s2 * (1.f / 1024.f) - mu * mu;
  float rs = rsqrtf(var + 1e-5f);
  float4 gg = ((const float4*)g)[tid];
  float4 bb = ((const float4*)be)[tid];
  float4 o;
  o.x = (v.x - mu) * rs * gg.x + bb.x;
  o.y = (v.y - mu) * rs * gg.y + bb.y;
  o.z = (v.z - mu) * rs * gg.z + bb.z;
  o.w = (v.w - mu) * rs * gg.w + bb.w;
  ((float4*)p)[tid] = o;
}

extern "C" void kernel_launch(void* const* d_in, const int* in_sizes, int n_in,
                              void* d_out, int out_size, void* d_ws, size_t ws_size,
                              hipStream_t stream) {
  (void)in_sizes; (void)n_in; (void)out_size; (void)ws_size;
  const float* w      = (const float*)d_in[0];
  const float* r_emb  = (const float*)d_in[1];
  const float* r_wb   = (const float*)d_in[2];
  const float* r_bias = (const float*)d_in[3];
  const float* qkv_w  = (const float*)d_in[4];
  const float* o_w    = (const float*)d_in[5];
  const float* ln_g   = (const float*)d_in[6];
  const float* ln_b   = (const float*)d_in[7];
  float* out = (float*)d_out;
  char* ws = (char*)d_ws;

  // workspace layout (bytes); total 77,594,624
  u16* w_b    = (u16*)(ws + 0);          // 16 MB; reused as attn_vec after QKV GEMM
  u16* qkvw_t = (u16*)(ws + 16777216);   // 6 MB  [3072][1024]
  u16* ow_t   = (u16*)(ws + 23068672);   // 2 MB  [1024][1024]
  u16* remb_t = (u16*)(ws + 25165824);   // 2 MB  [n][j][d]
  u16* q_b    = (u16*)(ws + 27262976);   // 16 MB [b][h][i][d]
  u16* k_b    = (u16*)(ws + 44040192);   // 16 MB [b][h][j][d]
  u16* vt_b   = (u16*)(ws + 60817408);   // 16 MB [b][h][d][j]  (transposed!)
  u16* av_b   = w_b;

  cast_w_k<<<8192, 256, 0, stream>>>(w, w_b);
  transpose_cast_k<<<dim3(96, 32), 256, 0, stream>>>(qkv_w, qkvw_t, 1024, 3072);
  transpose_cast_k<<<dim3(32, 32), 256, 0, stream>>>(o_w, ow_t, 1024, 1024);
  cast_remb_k<<<512, 256, 0, stream>>>(r_emb, remb_t);
  gemm_bt<0><<<dim3(24, 64), 256, 0, stream>>>(w_b, qkvw_t, 1024, q_b, k_b, vt_b, nullptr, nullptr);
  attn_k<<<dim3(2048), 256, 0, stream>>>(q_b, k_b, vt_b, remb_t, r_bias, r_wb, av_b);
  gemm_bt<1><<<dim3(8, 64), 256, 0, stream>>>(av_b, ow_t, 1024, nullptr, nullptr, nullptr, w, out);
  ln_k<<<8192, 256, 0, stream>>>(out, ln_g, ln_b);
}